// Round 8
// baseline (167.675 us; speedup 1.0000x reference)
//
#include <hip/hip_runtime.h>
#include <stdint.h>

// Fused MLP decode, MFMA f16. ROUND 8: modulo-2 pipeline (R7) + register
// diet to cross the 128-unified-reg occupancy cliff (m69: waves/SIMD halve
// at 64/128/256 unified regs).
// Cross-round curve: unified 128->31% occ, 136->29%, 144->25.5% (R7).
// Cuts (-48 unified):
//   - woutq f32x4[4] -> packed half2[8]; dot via v_fma_mix (free).
//   - b1 C-operand -> packed half2[8]; bias via 16 v_fma_mix/tile (cheap).
//   - W1 evicted to LDS, read per-tile at phase2 start with OPAQUE index
//     (defeats LICM; R2/R4 lesson). Unlike R4 (serial-chain regression at
//     2 waves), the R7 pipeline gives phase2's DS burst a full iteration
//     of slack and ~4 resident waves to cover the ~120cy latency.
// Structure otherwise = R7 (passed): phase2(tile k-1) || phase1(tile k)
// through double-buffered per-wave H; swapped L1 mfma(w1,Y); per-lane Wout
// dot + 2 shfl_xor; scale-folded u-domain silu; Chebyshev feature chain;
// W0 AGPR-resident; tix/rho 2-ahead + emb 1-ahead prefetch; grid 1024.

typedef _Float16 half8  __attribute__((ext_vector_type(8)));
typedef _Float16 half4v __attribute__((ext_vector_type(4)));
typedef _Float16 half2v __attribute__((ext_vector_type(2)));
typedef float f32x4 __attribute__((ext_vector_type(4)));

#define LOG2E 1.44269504088896340736f
#define NLN2  -0.6931471805599453f         // -ln2 = 1/(-log2e)
#define CSCL  -1.44269504088896340736f     // c = -log2e
#define BASE_LOGIT -0.84729786038720367f   // log(0.3/0.7)
#define CSANMAX 28700.0f
#define IC_VAL 8610.0f                     // 0.3 * 28700

__device__ __forceinline__ float fast_exp2(float x) { return __builtin_amdgcn_exp2f(x); }
__device__ __forceinline__ float fast_rcp(float x)  { return __builtin_amdgcn_rcpf(x); }
// u-domain pair silu: inputs u0,u1 (= c*x). outputs p = u*sigma = c*silu(x).
__device__ __forceinline__ void usilu2(float u0, float u1, float& p0, float& p1) {
  const float d0 = 1.0f + fast_exp2(u0);
  const float d1 = 1.0f + fast_exp2(u1);
  const float r  = fast_rcp(d0 * d1);
  p0 = u0 * d1 * r;
  p1 = u1 * d0 * r;
}
__device__ __forceinline__ half2v pkh(float a, float b) {
  return __builtin_bit_cast(half2v, __builtin_amdgcn_cvt_pkrtz(a, b));
}

union H8 { half8 v8; half2v v2[4]; half4v v4[2]; };
union H4 { half4v v4; half2v v2[2]; };

__global__ __launch_bounds__(256, 3) void mlp_kernel(
    const int* __restrict__ tix, const float* __restrict__ rho,
    const float* __restrict__ emb, const float* __restrict__ W0,
    const float* __restrict__ b0, const float* __restrict__ W1,
    const float* __restrict__ b1, const float* __restrict__ Wout,
    const float* __restrict__ bout, float* __restrict__ out, int ntiles)
{
  // W0 staging (init only) unions with the double-buffered per-wave H.
  // stage0 = 8192 B; H = 18432 B. Union = 18432 B. W1 persistent: 8192 B.
  __shared__ __align__(16) union {
    _Float16 stage0[2][4][64][8];
    _Float16 H[4][2][16][72];       // stride 144 B rows -> 2-way banks (free)
  } shA;
  __shared__ __align__(16) _Float16 Wlds1[2][4][64][8];

  const int tid  = threadIdx.x;
  const int wid  = tid >> 6;
  const int lane = tid & 63;
  const int m    = lane & 15;
  const int q    = lane >> 4;

  _Float16 (*Hb2)[16][72] = shA.H[wid];   // [2][16][72]

  // ---- init: wave 0 builds the swizzled weight fragments ----
  // content B[k=s*32+q*8+j][n=t*16+m]; same lane layout serves as A-op
  // (=> W^T) or B-op. L0 feature rows PERMUTED: k-window 32..63 =
  // [cos1..8|sin1..8|rho,b0(1.0),0pad]. L0 fragments PRE-SCALED by c.
  if (wid == 0) {
#pragma unroll
    for (int t = 0; t < 4; ++t) {
#pragma unroll
      for (int s = 0; s < 2; ++s) {
        half8 f0, f1;
#pragma unroll
        for (int j = 0; j < 8; ++j) {
          const int k = s * 32 + q * 8 + j;
          const int n = t * 16 + m;
          float v0;
          if (k < 32) {
            v0 = W0[k * 64 + n];
          } else {
            const int kn = k - 32;
            v0 = (kn < 16) ? W0[(33 + kn) * 64 + n]
               : (kn == 16) ? W0[32 * 64 + n]
               : (kn == 17) ? b0[n] : 0.0f;
          }
          f0[j] = (_Float16)(CSCL * v0);
          f1[j] = (_Float16)W1[k * 64 + n];   // W1 UNSCALED (c rides through p)
        }
        *(half8*)&shA.stage0[s][t][lane][0] = f0;
        *(half8*)&Wlds1[s][t][lane][0] = f1;
      }
    }
  }

  // ---- persistent epilogue constants, PACKED f16 (SWAPPED L1 layout) ----
  // lane (q,m) owns hidden h = t*16 + q*4 + r. Consumed via v_fma_mix.
  half2v biash[8];   // c * b1[h], pairs (r=2j, 2j+1) per t
  half2v wouth[8];   // -ln2 * Wout[h]
#pragma unroll
  for (int t = 0; t < 4; ++t) {
    const f32x4 bv = *(const f32x4*)(b1 + t * 16 + q * 4);
    const f32x4 wv = *(const f32x4*)(Wout + t * 16 + q * 4);
    biash[t * 2]     = pkh(CSCL * bv[0], CSCL * bv[1]);
    biash[t * 2 + 1] = pkh(CSCL * bv[2], CSCL * bv[3]);
    wouth[t * 2]     = pkh(NLN2 * wv[0], NLN2 * wv[1]);
    wouth[t * 2 + 1] = pkh(NLN2 * wv[2], NLN2 * wv[3]);
  }
  const float boutBL = bout[0] + BASE_LOGIT;

  __syncthreads();   // staged weights visible

  // ---- hoist W0 fragments only (32 regs); W1 stays in LDS ----
  half8 w0A[4], w0B[4];
#pragma unroll
  for (int t = 0; t < 4; ++t) {
    w0A[t] = *(const half8*)&shA.stage0[0][t][lane][0];
    w0B[t] = *(const half8*)&shA.stage0[1][t][lane][0];
  }

  __syncthreads();   // stage0 reads done; H may overwrite

  const half8* wb1 = (const half8*)&Wlds1[0][0][0][0];
  const f32x4 z = {0.0f, 0.0f, 0.0f, 0.0f};
  const int S = gridDim.x * 4;

  int tg = blockIdx.x * 4 + wid;
  if (tg >= ntiles) return;          // after both barriers: safe
  const int lim = ntiles - 1;

  // ---- phase1: feat -> L0 -> silu -> H[wb] ----
  auto phase1 = [&](float rhp, half8 X0v, int wb) {
    const float rev = 0.5f * rhp;  // v_sin/v_cos take revolutions
    const float c1  = __builtin_amdgcn_cosf(rev);
    const float s1f = __builtin_amdgcn_sinf(rev);
    const float tc  = 2.0f * c1;
    const float x1v = (q == 0) ? c1 : ((q == 1) ? s1f : 0.0f);
    const float x0v = (q == 0) ? 1.0f : 0.0f;
    const float x2v = tc * x1v - x0v;
    const float x3v = tc * x2v - x1v;
    const float x4v = tc * x3v - x2v;
    const float x5v = tc * x4v - x3v;
    const float x6v = tc * x5v - x4v;
    const float x7v = tc * x6v - x5v;
    const float x8v = tc * x7v - x6v;
    H8 X1;
    X1.v2[0] = (q == 2) ? pkh(rhp, 1.0f) : pkh(x1v, x2v);  // q==2: (rho, b0-slot)
    X1.v2[1] = pkh(x3v, x4v);
    X1.v2[2] = pkh(x5v, x6v);
    X1.v2[3] = pkh(x7v, x8v);

    f32x4 acc[4];
#pragma unroll
    for (int t = 0; t < 4; ++t) {
      f32x4 a = __builtin_amdgcn_mfma_f32_16x16x32_f16(w0A[t], X0v, z, 0, 0, 0);
      a = __builtin_amdgcn_mfma_f32_16x16x32_f16(w0B[t], X1.v8, a, 0, 0, 0);
      acc[t] = a;
    }
#pragma unroll
    for (int t = 0; t < 4; ++t) {
      float p0, p1, p2, p3;
      usilu2(acc[t][0], acc[t][1], p0, p1);
      usilu2(acc[t][2], acc[t][3], p2, p3);
      H4 hh;
      hh.v2[0] = pkh(p0, p1);
      hh.v2[1] = pkh(p2, p3);
      *(half4v*)&Hb2[wb][m][t * 16 + q * 4] = hh.v4;
    }
  };

  // ---- phase2: {W1,Y} ds_reads -> L1 -> bias(mix) -> silu -> dot -> store ----
  auto phase2 = [&](int rb, int tgS, int icS) {
    // OPAQUE index: stops LICM from hoisting the W1 reads back into regs.
    int z0 = 0;
    asm volatile("" : "+v"(z0));
    half8 w1A[4], w1B[4];
#pragma unroll
    for (int t = 0; t < 4; ++t) {
      w1A[t] = wb1[z0 + t * 64 + lane];
      w1B[t] = wb1[z0 + (4 + t) * 64 + lane];
    }
    const half8 Y0 = *(const half8*)&Hb2[rb][m][q * 8];     // written 1 iter ago
    const half8 Y1 = *(const half8*)&Hb2[rb][m][32 + q * 8];
    f32x4 acc[4];
#pragma unroll
    for (int t = 0; t < 4; ++t) {
      f32x4 a = __builtin_amdgcn_mfma_f32_16x16x32_f16(w1A[t], Y0, z, 0, 0, 0);
      a = __builtin_amdgcn_mfma_f32_16x16x32_f16(w1B[t], Y1, a, 0, 0, 0);
      acc[t] = a;
    }
    float dA = 0.0f, dB = 0.0f;
#pragma unroll
    for (int t = 0; t < 4; ++t) {
      float p0, p1, p2, p3;
      // u = acc + c*b1 (v_fma_mix: f16 src folded, no unpack cost)
      const float u0 = fmaf((float)biash[t * 2][0],     1.0f, acc[t][0]);
      const float u1 = fmaf((float)biash[t * 2][1],     1.0f, acc[t][1]);
      const float u2 = fmaf((float)biash[t * 2 + 1][0], 1.0f, acc[t][2]);
      const float u3 = fmaf((float)biash[t * 2 + 1][1], 1.0f, acc[t][3]);
      usilu2(u0, u1, p0, p1);
      usilu2(u2, u3, p2, p3);
      dA = fmaf(p0, (float)wouth[t * 2][0],     dA);
      dB = fmaf(p1, (float)wouth[t * 2][1],     dB);
      dA = fmaf(p2, (float)wouth[t * 2 + 1][0], dA);
      dB = fmaf(p3, (float)wouth[t * 2 + 1][1], dB);
    }
    float dot = dA + dB;
    dot += __shfl_xor(dot, 16, 64);
    dot += __shfl_xor(dot, 32, 64);
    const float theta = fast_rcp(1.0f + fast_exp2(-LOG2E * (dot + boutBL)));
    const float val = (icS == 0) ? IC_VAL : theta * CSANMAX;
    if (q == 0) out[tgS * 16 + m] = val;
  };

  // ---- prologue: fill the pipe with tile tg ----
  int   tC = tix[tg * 16 + m];
  float rC = rho[tg * 16 + m];
  const int tg1 = min(tg + S, lim);
  int   tN = tix[tg1 * 16 + m];
  float rN = rho[tg1 * 16 + m];
  const int tg2 = min(tg + 2 * S, lim);
  int   tNN0 = tix[tg2 * 16 + m];
  float rNN0 = rho[tg2 * 16 + m];

  H8 X0C;
  {
    const int idx = min(max(tC - 1, 0), 510);
    const float* e = emb + (size_t)idx * 32 + q * 8;
    const f32x4 e0 = *(const f32x4*)e;
    const f32x4 e1 = *(const f32x4*)(e + 4);
    X0C.v2[0] = pkh(e0[0], e0[1]); X0C.v2[1] = pkh(e0[2], e0[3]);
    X0C.v2[2] = pkh(e1[0], e1[1]); X0C.v2[3] = pkh(e1[2], e1[3]);
  }
  phase1(rC, X0C.v8, 0);
  int icP = tC, tgP = tg;
  {
    const int idx = min(max(tN - 1, 0), 510);
    const float* e = emb + (size_t)idx * 32 + q * 8;
    const f32x4 e0 = *(const f32x4*)e;
    const f32x4 e1 = *(const f32x4*)(e + 4);
    X0C.v2[0] = pkh(e0[0], e0[1]); X0C.v2[1] = pkh(e0[2], e0[3]);
    X0C.v2[2] = pkh(e1[0], e1[1]); X0C.v2[3] = pkh(e1[2], e1[3]);
  }
  tC = tN; rC = rN;
  tN = tNN0; rN = rNN0;

  int wbuf = 1;
  tg += S;

  // ---- steady state: phase2(prev tile) || phase1(current tile) ----
  while (tg < ntiles) {
    // prefetch tix/rho 2 tiles ahead (clamped, branchless)
    const int tgn2 = min(tg + 2 * S, lim);
    const int   tNN = tix[tgn2 * 16 + m];
    const float rNN = rho[tgn2 * 16 + m];
    // emb load for NEXT tile (tN arrived >=1 iteration ago)
    const int idxN = min(max(tN - 1, 0), 510);
    const float* ern = emb + (size_t)idxN * 32 + q * 8;
    const f32x4 eN0 = *(const f32x4*)ern;
    const f32x4 eN1 = *(const f32x4*)(ern + 4);

    phase2(wbuf ^ 1, tgP, icP);      // finish PREVIOUS tile (independent...)
    phase1(rC, X0C.v8, wbuf);        // ...of starting CURRENT tile

    icP = tC; tgP = tg;
    // pack next tile's emb (vmem slack = phase2+phase1 above)
    X0C.v2[0] = pkh(eN0[0], eN0[1]); X0C.v2[1] = pkh(eN0[2], eN0[3]);
    X0C.v2[2] = pkh(eN1[0], eN1[1]); X0C.v2[3] = pkh(eN1[2], eN1[3]);
    tC = tN; rC = rN;
    tN = tNN; rN = rNN;
    wbuf ^= 1;
    tg += S;
  }

  // ---- epilogue: drain the last tile ----
  phase2(wbuf ^ 1, tgP, icP);
}

extern "C" void kernel_launch(void* const* d_in, const int* in_sizes, int n_in,
                              void* d_out, int out_size, void* d_ws, size_t ws_size,
                              hipStream_t stream) {
  const int*   tix  = (const int*)d_in[0];
  const float* rho  = (const float*)d_in[1];
  const float* emb  = (const float*)d_in[2];
  const float* W0   = (const float*)d_in[3];
  const float* b0   = (const float*)d_in[4];
  const float* W1   = (const float*)d_in[5];
  const float* b1   = (const float*)d_in[6];
  const float* Wout = (const float*)d_in[7];
  const float* bout = (const float*)d_in[8];
  float* outp = (float*)d_out;

  const int n      = in_sizes[0];    // 2,000,000 (divisible by 16)
  const int ntiles = n / 16;         // 125,000 tiles of 16 points

  // 4-wave blocks, 26624 B LDS (4 blocks/CU -> 106 KB, never the cap).
  int grid = 1024;
  const int maxg = (ntiles + 3) / 4;
  if (grid > maxg) grid = maxg;
  mlp_kernel<<<dim3(grid), dim3(256), 0, stream>>>(
      tix, rho, emb, W0, b0, W1, b1, Wout, bout, outp, ntiles);
}